// Round 5
// baseline (134.803 us; speedup 1.0000x reference)
//
#include <hip/hip_runtime.h>
#include <cstdint>

#define T_SEQ 4096
#define E_DIM 1024
#define N_B   8
#define SC    64       // seq positions per block
typedef float v2f __attribute__((ext_vector_type(2)));

constexpr int LW[4] = {2, 8, 12, 6};

// dec_lo
constexpr float DLf[4][12] = {
  {0.7071067811865476f, 0.7071067811865476f, 0,0,0,0,0,0,0,0,0,0},
  {-0.010597401784997278f, 0.032883011666982945f, 0.030841381835986965f, -0.18703481171888114f,
   -0.02798376941698385f, 0.6308807679295904f, 0.7148465705525415f, 0.23037781330885523f, 0,0,0,0},
  {-0.007800708325034148f, 0.0017677118642428036f, 0.04472490177066578f, -0.021060292512300564f,
   -0.07263752278646252f, 0.3379294217276218f, 0.787641141030194f, 0.4910559419267466f,
   -0.048311742585633f, -0.11799011114819057f, 0.0034907120842174702f, 0.015404109327027373f},
  {-0.08838834764831845f, 0.08838834764831845f, 0.7071067811865476f, 0.7071067811865476f,
    0.08838834764831845f, -0.08838834764831845f, 0,0,0,0,0,0},
};
// dec_hi
constexpr float DHf[4][12] = {
  {-0.7071067811865476f, 0.7071067811865476f, 0,0,0,0,0,0,0,0,0,0},
  {-0.23037781330885523f, 0.7148465705525415f, -0.6308807679295904f, -0.02798376941698385f,
    0.18703481171888114f, 0.030841381835986965f, -0.032883011666982945f, -0.010597401784997278f, 0,0,0,0},
  {-0.015404109327027373f, 0.0034907120842174702f, 0.11799011114819057f, -0.048311742585633f,
   -0.4910559419267466f, 0.787641141030194f, -0.3379294217276218f, -0.07263752278646252f,
    0.021060292512300564f, 0.04472490177066578f, -0.0017677118642428036f, -0.007800708325034148f},
  {0,0,-0.7071067811865476f, 0.7071067811865476f, 0,0, 0,0,0,0,0,0},
};
// rec_lo
constexpr float RLf[4][12] = {
  {0.7071067811865476f, 0.7071067811865476f, 0,0,0,0,0,0,0,0,0,0},
  {0.23037781330885523f, 0.7148465705525415f, 0.6308807679295904f, -0.02798376941698385f,
   -0.18703481171888114f, 0.030841381835986965f, 0.032883011666982945f, -0.010597401784997278f, 0,0,0,0},
  {0.015404109327027373f, 0.0034907120842174702f, -0.11799011114819057f, -0.048311742585633f,
   0.4910559419267466f, 0.787641141030194f, 0.3379294217276218f, -0.07263752278646252f,
   -0.021060292512300564f, 0.04472490177066578f, 0.0017677118642428036f, -0.007800708325034148f},
  {0,0,0.7071067811865476f, 0.7071067811865476f, 0,0, 0,0,0,0,0,0},
};
// rec_hi
constexpr float RHf[4][12] = {
  {0.7071067811865476f, -0.7071067811865476f, 0,0,0,0,0,0,0,0,0,0},
  {-0.010597401784997278f, -0.032883011666982945f, 0.030841381835986965f, 0.18703481171888114f,
   -0.02798376941698385f, -0.6308807679295904f, 0.7148465705525415f, -0.23037781330885523f, 0,0,0,0},
  {-0.007800708325034148f, -0.0017677118642428036f, 0.04472490177066578f, 0.021060292512300564f,
   -0.07263752278646252f, -0.3379294217276218f, 0.787641141030194f, -0.4910559419267466f,
   -0.048311742585633f, 0.11799011114819057f, 0.0034907120842174702f, -0.015404109327027373f},
  {-0.08838834764831845f, -0.08838834764831845f, 0.7071067811865476f, -0.7071067811865476f,
    0.08838834764831845f, 0.08838834764831845f, 0,0,0,0,0,0},
};

__device__ __forceinline__ v2f sv(float c) { return v2f{c, c}; }

template <int W>
__device__ __forceinline__ void wavelet_accum(const v2f (&xw)[36], v2f (&acc)[16],
                                              v2f la, v2f ld, v2f gw) {
  constexpr int L  = LW[W];
  constexpr int KT = L / 2 + 7;   // kk in [0, L/2+6]; covers outputs j in [0,16)
#pragma unroll
  for (int kk = 0; kk < KT; ++kk) {
    v2f lo = {0.f, 0.f}, hi = {0.f, 0.f};
#pragma unroll
    for (int m = 0; m < L; ++m) {
      const v2f xv = xw[2 * kk + 11 - m];
      if (DLf[W][m] != 0.0f) lo += sv(DLf[W][m]) * xv;
      if (DHf[W][m] != 0.0f) hi += sv(DHf[W][m]) * xv;
    }
    v2f cl, ch;
    cl.x = __builtin_amdgcn_fmed3f(lo.x, -la.x, la.x);
    cl.y = __builtin_amdgcn_fmed3f(lo.y, -la.y, la.y);
    ch.x = __builtin_amdgcn_fmed3f(hi.x, -ld.x, ld.x);
    ch.y = __builtin_amdgcn_fmed3f(hi.y, -ld.y, ld.y);
    const v2f loS = (lo - cl) * gw;
    const v2f hiS = (hi - ch) * gw;
#pragma unroll
    for (int m = 0; m < L; ++m) {
      const int j = 2 * kk + m + 2 - L;   // compile-time after unroll
      if (j >= 0 && j < 16) {
        if (RLf[W][m] != 0.0f) acc[j] += loS * sv(RLf[W][m]);
        if (RHf[W][m] != 0.0f) acc[j] += hiS * sv(RHf[W][m]);
      }
    }
  }
}

// No LDS: each thread owns channels (e0+2*lane, e0+2*lane+1) and 16 seq
// positions; window loads are coalesced global_load_dwordx2 (512B per wave
// per position), halo reuse served by L1/L2. Occupancy VGPR-limited.
__global__ __launch_bounds__(256, 4) void wlm_k1(
    const float* __restrict__ x,
    const float* __restrict__ la_, const float* __restrict__ ld_,
    const float* __restrict__ lg_, const float* __restrict__ th_,
    const float* __restrict__ bl_, float* __restrict__ y) {
  const int tid  = threadIdx.x;
  const int lane = tid & 63;
  const int wave = tid >> 6;
  const int s0 = blockIdx.x * SC;
  const int e0 = blockIdx.y * 128;
  const int b  = blockIdx.z;
  const int e  = e0 + 2 * lane;
  const int sA = s0 + wave * 16;

  // ---- window: x_ref[sA-10 .. sA+25] for channel pair (e, e+1) ----
  const size_t rowb = (size_t)b * T_SEQ;
  v2f xw[36];
#pragma unroll
  for (int i = 0; i < 36; ++i) {
    int g = sA - 10 + i;
    g = (g < 0) ? -g : g;
    g = (g >= T_SEQ) ? (2 * T_SEQ - 2 - g) : g;
    xw[i] = *reinterpret_cast<const v2f*>(&x[(rowb + g) * E_DIM + e]);
  }

  // ---- per-channel-pair params ----
  const v2f la = *reinterpret_cast<const v2f*>(&la_[e]);
  const v2f ld = *reinterpret_cast<const v2f*>(&ld_[e]);
  const v2f lg = *reinterpret_cast<const v2f*>(&lg_[e]);
  const v2f th = *reinterpret_cast<const v2f*>(&th_[e]);
  v2f g2;
  g2.x = (fmaxf(lg.x, 0.f) + log1pf(expf(-fabsf(lg.x))) + 1e-6f) * cosf(th.x);
  g2.y = (fmaxf(lg.y, 0.f) + log1pf(expf(-fabsf(lg.y))) + 1e-6f) * cosf(th.y);

  const float b0 = bl_[0], b1 = bl_[1], b2 = bl_[2], b3 = bl_[3];
  const float mx = fmaxf(fmaxf(b0, b1), fmaxf(b2, b3));
  const float w0 = expf(b0 - mx), w1 = expf(b1 - mx),
              w2 = expf(b2 - mx), w3 = expf(b3 - mx);
  const float wr = 1.f / (w0 + w1 + w2 + w3);
  const v2f gw0 = g2 * sv(w0 * wr), gw1 = g2 * sv(w1 * wr),
            gw2 = g2 * sv(w2 * wr), gw3 = g2 * sv(w3 * wr);

  v2f acc[16];
#pragma unroll
  for (int j = 0; j < 16; ++j) acc[j] = v2f{0.f, 0.f};

  wavelet_accum<0>(xw, acc, la, ld, gw0);
  wavelet_accum<1>(xw, acc, la, ld, gw1);
  wavelet_accum<2>(xw, acc, la, ld, gw2);
  wavelet_accum<3>(xw, acc, la, ld, gw3);

  // ---- y = x + sum_i w_i * rec_i (channel pair per thread) ----
#pragma unroll
  for (int j = 0; j < 16; ++j) {
    const v2f o = xw[j + 10] + acc[j];
    *reinterpret_cast<v2f*>(&y[(rowb + sA + j) * E_DIM + e]) = o;
  }
}

__global__ __launch_bounds__(256) void wlm_k2(float* __restrict__ y,
                                              const float* __restrict__ w,
                                              const float* __restrict__ bias) {
  const int token = blockIdx.x;
  const int tid = threadIdx.x;
  float* row = y + (size_t)token * E_DIM;

  float4 v = *reinterpret_cast<const float4*>(&row[tid * 4]);
  float s  = v.x + v.y + v.z + v.w;
  float sq = v.x * v.x + v.y * v.y + v.z * v.z + v.w * v.w;
#pragma unroll
  for (int off = 32; off; off >>= 1) {
    s  += __shfl_down(s, off);
    sq += __shfl_down(sq, off);
  }
  __shared__ float ps[4], pq[4], stat[2];
  const int wave = tid >> 6, lane = tid & 63;
  if (lane == 0) { ps[wave] = s; pq[wave] = sq; }
  __syncthreads();
  if (tid == 0) {
    const float S1 = ps[0] + ps[1] + ps[2] + ps[3];
    const float S2 = pq[0] + pq[1] + pq[2] + pq[3];
    const float mu = S1 * (1.f / E_DIM);
    const float var = S2 * (1.f / E_DIM) - mu * mu;
    stat[0] = mu;
    stat[1] = rsqrtf(var + 1e-5f);
  }
  __syncthreads();
  const float mu = stat[0], rstd = stat[1];
  const float4 wv = *reinterpret_cast<const float4*>(&w[tid * 4]);
  const float4 bv = *reinterpret_cast<const float4*>(&bias[tid * 4]);
  float4 o;
  o.x = (v.x - mu) * rstd * wv.x + bv.x;
  o.y = (v.y - mu) * rstd * wv.y + bv.y;
  o.z = (v.z - mu) * rstd * wv.z + bv.z;
  o.w = (v.w - mu) * rstd * wv.w + bv.w;
  *reinterpret_cast<float4*>(&row[tid * 4]) = o;
}

extern "C" void kernel_launch(void* const* d_in, const int* in_sizes, int n_in,
                              void* d_out, int out_size, void* d_ws, size_t ws_size,
                              hipStream_t stream) {
  const float* x   = (const float*)d_in[0];
  const float* la  = (const float*)d_in[1];
  const float* ldt = (const float*)d_in[2];
  const float* lg  = (const float*)d_in[3];
  const float* th  = (const float*)d_in[4];
  const float* bl  = (const float*)d_in[5];
  const float* lnw = (const float*)d_in[6];
  const float* lnb = (const float*)d_in[7];
  float* out = (float*)d_out;

  dim3 g1(T_SEQ / SC, E_DIM / 128, N_B);  // (64, 8, 8)
  wlm_k1<<<g1, 256, 0, stream>>>(x, la, ldt, lg, th, bl, out);
  wlm_k2<<<dim3(N_B * T_SEQ), 256, 0, stream>>>(out, lnw, lnb);
}

// Round 6
// 111.962 us; speedup vs baseline: 1.2040x; 1.2040x over previous
//
#include <hip/hip_runtime.h>
#include <cstdint>

#define T_SEQ 4096
#define E_DIM 1024
#define N_B   8
#define SC    64       // seq positions per block
typedef float v2f __attribute__((ext_vector_type(2)));

constexpr int LW[4] = {2, 8, 12, 6};

// dec_lo
constexpr float DLf[4][12] = {
  {0.7071067811865476f, 0.7071067811865476f, 0,0,0,0,0,0,0,0,0,0},
  {-0.010597401784997278f, 0.032883011666982945f, 0.030841381835986965f, -0.18703481171888114f,
   -0.02798376941698385f, 0.6308807679295904f, 0.7148465705525415f, 0.23037781330885523f, 0,0,0,0},
  {-0.007800708325034148f, 0.0017677118642428036f, 0.04472490177066578f, -0.021060292512300564f,
   -0.07263752278646252f, 0.3379294217276218f, 0.787641141030194f, 0.4910559419267466f,
   -0.048311742585633f, -0.11799011114819057f, 0.0034907120842174702f, 0.015404109327027373f},
  {-0.08838834764831845f, 0.08838834764831845f, 0.7071067811865476f, 0.7071067811865476f,
    0.08838834764831845f, -0.08838834764831845f, 0,0,0,0,0,0},
};
// dec_hi
constexpr float DHf[4][12] = {
  {-0.7071067811865476f, 0.7071067811865476f, 0,0,0,0,0,0,0,0,0,0},
  {-0.23037781330885523f, 0.7148465705525415f, -0.6308807679295904f, -0.02798376941698385f,
    0.18703481171888114f, 0.030841381835986965f, -0.032883011666982945f, -0.010597401784997278f, 0,0,0,0},
  {-0.015404109327027373f, 0.0034907120842174702f, 0.11799011114819057f, -0.048311742585633f,
   -0.4910559419267466f, 0.787641141030194f, -0.3379294217276218f, -0.07263752278646252f,
    0.021060292512300564f, 0.04472490177066578f, -0.0017677118642428036f, -0.007800708325034148f},
  {0,0,-0.7071067811865476f, 0.7071067811865476f, 0,0, 0,0,0,0,0,0},
};
// rec_lo
constexpr float RLf[4][12] = {
  {0.7071067811865476f, 0.7071067811865476f, 0,0,0,0,0,0,0,0,0,0},
  {0.23037781330885523f, 0.7148465705525415f, 0.6308807679295904f, -0.02798376941698385f,
   -0.18703481171888114f, 0.030841381835986965f, 0.032883011666982945f, -0.010597401784997278f, 0,0,0,0},
  {0.015404109327027373f, 0.0034907120842174702f, -0.11799011114819057f, -0.048311742585633f,
   0.4910559419267466f, 0.787641141030194f, 0.3379294217276218f, -0.07263752278646252f,
   -0.021060292512300564f, 0.04472490177066578f, 0.0017677118642428036f, -0.007800708325034148f},
  {0,0,0.7071067811865476f, 0.7071067811865476f, 0,0, 0,0,0,0,0,0},
};
// rec_hi
constexpr float RHf[4][12] = {
  {0.7071067811865476f, -0.7071067811865476f, 0,0,0,0,0,0,0,0,0,0},
  {-0.010597401784997278f, -0.032883011666982945f, 0.030841381835986965f, 0.18703481171888114f,
   -0.02798376941698385f, -0.6308807679295904f, 0.7148465705525415f, -0.23037781330885523f, 0,0,0,0},
  {-0.007800708325034148f, -0.0017677118642428036f, 0.04472490177066578f, 0.021060292512300564f,
   -0.07263752278646252f, -0.3379294217276218f, 0.787641141030194f, -0.4910559419267466f,
   -0.048311742585633f, 0.11799011114819057f, 0.0034907120842174702f, -0.015404109327027373f},
  {-0.08838834764831845f, -0.08838834764831845f, 0.7071067811865476f, -0.7071067811865476f,
    0.08838834764831845f, 0.08838834764831845f, 0,0,0,0,0,0},
};

__device__ __forceinline__ v2f sv(float c) { return v2f{c, c}; }

template <int W>
__device__ __forceinline__ void wavelet_accum(const v2f (&xw)[36], v2f (&acc)[16],
                                              v2f la, v2f ld, v2f gw) {
  constexpr int L  = LW[W];
  constexpr int KT = L / 2 + 7;   // kk in [0, L/2+6]; covers outputs j in [0,16)
#pragma unroll
  for (int kk = 0; kk < KT; ++kk) {
    v2f lo = {0.f, 0.f}, hi = {0.f, 0.f};
#pragma unroll
    for (int m = 0; m < L; ++m) {
      const v2f xv = xw[2 * kk + 11 - m];
      if (DLf[W][m] != 0.0f) lo += sv(DLf[W][m]) * xv;
      if (DHf[W][m] != 0.0f) hi += sv(DHf[W][m]) * xv;
    }
    v2f cl, ch;
    cl.x = __builtin_amdgcn_fmed3f(lo.x, -la.x, la.x);
    cl.y = __builtin_amdgcn_fmed3f(lo.y, -la.y, la.y);
    ch.x = __builtin_amdgcn_fmed3f(hi.x, -ld.x, ld.x);
    ch.y = __builtin_amdgcn_fmed3f(hi.y, -ld.y, ld.y);
    const v2f loS = (lo - cl) * gw;
    const v2f hiS = (hi - ch) * gw;
#pragma unroll
    for (int m = 0; m < L; ++m) {
      const int j = 2 * kk + m + 2 - L;   // compile-time after unroll
      if (j >= 0 && j < 16) {
        if (RLf[W][m] != 0.0f) acc[j] += loS * sv(RLf[W][m]);
        if (RHf[W][m] != 0.0f) acc[j] += hiS * sv(RHf[W][m]);
      }
    }
  }
}

// No LDS; channel pair (e, e+1) per thread, 16 positions per thread.
// amdgpu_waves_per_eu(3,4): max occupancy 4 waves/EU -> compiler has no
// incentive to compress below ~128 VGPR (R5 showed it chose 64 and
// spilled/rematerialized, pinning the kernel at ~105us latency-bound).
__global__ __launch_bounds__(256)
__attribute__((amdgpu_waves_per_eu(3, 4)))
void wlm_k1(
    const float* __restrict__ x,
    const float* __restrict__ la_, const float* __restrict__ ld_,
    const float* __restrict__ lg_, const float* __restrict__ th_,
    const float* __restrict__ bl_, float* __restrict__ y) {
  const int tid  = threadIdx.x;
  const int lane = tid & 63;
  const int wave = tid >> 6;
  const int s0 = blockIdx.x * SC;
  const int e0 = blockIdx.y * 128;
  const int b  = blockIdx.z;
  const int e  = e0 + 2 * lane;
  const int sA = s0 + wave * 16;

  // ---- window: x_ref[sA-10 .. sA+25] for channel pair (e, e+1) ----
  const size_t rowb = (size_t)b * T_SEQ;
  v2f xw[36];
  if (sA >= 10 && sA + 26 <= T_SEQ) {
    // interior: no reflect, pure strided loads (uniform branch per wave)
    const float* p = &x[(rowb + sA - 10) * E_DIM + e];
#pragma unroll
    for (int i = 0; i < 36; ++i) {
      xw[i] = *reinterpret_cast<const v2f*>(p + (size_t)i * E_DIM);
    }
  } else {
#pragma unroll
    for (int i = 0; i < 36; ++i) {
      int g = sA - 10 + i;
      g = (g < 0) ? -g : g;
      g = (g >= T_SEQ) ? (2 * T_SEQ - 2 - g) : g;
      xw[i] = *reinterpret_cast<const v2f*>(&x[(rowb + g) * E_DIM + e]);
    }
  }

  // ---- per-channel-pair params ----
  const v2f la = *reinterpret_cast<const v2f*>(&la_[e]);
  const v2f ld = *reinterpret_cast<const v2f*>(&ld_[e]);
  const v2f lg = *reinterpret_cast<const v2f*>(&lg_[e]);
  const v2f th = *reinterpret_cast<const v2f*>(&th_[e]);
  v2f g2;
  g2.x = (fmaxf(lg.x, 0.f) + log1pf(expf(-fabsf(lg.x))) + 1e-6f) * cosf(th.x);
  g2.y = (fmaxf(lg.y, 0.f) + log1pf(expf(-fabsf(lg.y))) + 1e-6f) * cosf(th.y);

  const float b0 = bl_[0], b1 = bl_[1], b2 = bl_[2], b3 = bl_[3];
  const float mx = fmaxf(fmaxf(b0, b1), fmaxf(b2, b3));
  const float w0 = expf(b0 - mx), w1 = expf(b1 - mx),
              w2 = expf(b2 - mx), w3 = expf(b3 - mx);
  const float wr = 1.f / (w0 + w1 + w2 + w3);
  const v2f gw0 = g2 * sv(w0 * wr), gw1 = g2 * sv(w1 * wr),
            gw2 = g2 * sv(w2 * wr), gw3 = g2 * sv(w3 * wr);

  v2f acc[16];
#pragma unroll
  for (int j = 0; j < 16; ++j) acc[j] = v2f{0.f, 0.f};

  wavelet_accum<0>(xw, acc, la, ld, gw0);
  wavelet_accum<1>(xw, acc, la, ld, gw1);
  wavelet_accum<2>(xw, acc, la, ld, gw2);
  wavelet_accum<3>(xw, acc, la, ld, gw3);

  // ---- y = x + sum_i w_i * rec_i (channel pair per thread) ----
#pragma unroll
  for (int j = 0; j < 16; ++j) {
    const v2f o = xw[j + 10] + acc[j];
    *reinterpret_cast<v2f*>(&y[(rowb + sA + j) * E_DIM + e]) = o;
  }
}

__global__ __launch_bounds__(256) void wlm_k2(float* __restrict__ y,
                                              const float* __restrict__ w,
                                              const float* __restrict__ bias) {
  const int token = blockIdx.x;
  const int tid = threadIdx.x;
  float* row = y + (size_t)token * E_DIM;

  float4 v = *reinterpret_cast<const float4*>(&row[tid * 4]);
  float s  = v.x + v.y + v.z + v.w;
  float sq = v.x * v.x + v.y * v.y + v.z * v.z + v.w * v.w;
#pragma unroll
  for (int off = 32; off; off >>= 1) {
    s  += __shfl_down(s, off);
    sq += __shfl_down(sq, off);
  }
  __shared__ float ps[4], pq[4], stat[2];
  const int wave = tid >> 6, lane = tid & 63;
  if (lane == 0) { ps[wave] = s; pq[wave] = sq; }
  __syncthreads();
  if (tid == 0) {
    const float S1 = ps[0] + ps[1] + ps[2] + ps[3];
    const float S2 = pq[0] + pq[1] + pq[2] + pq[3];
    const float mu = S1 * (1.f / E_DIM);
    const float var = S2 * (1.f / E_DIM) - mu * mu;
    stat[0] = mu;
    stat[1] = rsqrtf(var + 1e-5f);
  }
  __syncthreads();
  const float mu = stat[0], rstd = stat[1];
  const float4 wv = *reinterpret_cast<const float4*>(&w[tid * 4]);
  const float4 bv = *reinterpret_cast<const float4*>(&bias[tid * 4]);
  float4 o;
  o.x = (v.x - mu) * rstd * wv.x + bv.x;
  o.y = (v.y - mu) * rstd * wv.y + bv.y;
  o.z = (v.z - mu) * rstd * wv.z + bv.z;
  o.w = (v.w - mu) * rstd * wv.w + bv.w;
  *reinterpret_cast<float4*>(&row[tid * 4]) = o;
}

extern "C" void kernel_launch(void* const* d_in, const int* in_sizes, int n_in,
                              void* d_out, int out_size, void* d_ws, size_t ws_size,
                              hipStream_t stream) {
  const float* x   = (const float*)d_in[0];
  const float* la  = (const float*)d_in[1];
  const float* ldt = (const float*)d_in[2];
  const float* lg  = (const float*)d_in[3];
  const float* th  = (const float*)d_in[4];
  const float* bl  = (const float*)d_in[5];
  const float* lnw = (const float*)d_in[6];
  const float* lnb = (const float*)d_in[7];
  float* out = (float*)d_out;

  dim3 g1(T_SEQ / SC, E_DIM / 128, N_B);  // (64, 8, 8)
  wlm_k1<<<g1, 256, 0, stream>>>(x, la, ldt, lg, th, bl, out);
  wlm_k2<<<dim3(N_B * T_SEQ), 256, 0, stream>>>(out, lnw, lnb);
}

// Round 7
// 111.861 us; speedup vs baseline: 1.2051x; 1.0009x over previous
//
#include <hip/hip_runtime.h>
#include <cstdint>

#define T_SEQ 4096
#define E_DIM 1024
#define N_B   8
#define SC    64       // seq positions per block
typedef float v2f __attribute__((ext_vector_type(2)));

constexpr int LW[4] = {2, 8, 12, 6};

// dec_lo
constexpr float DLf[4][12] = {
  {0.7071067811865476f, 0.7071067811865476f, 0,0,0,0,0,0,0,0,0,0},
  {-0.010597401784997278f, 0.032883011666982945f, 0.030841381835986965f, -0.18703481171888114f,
   -0.02798376941698385f, 0.6308807679295904f, 0.7148465705525415f, 0.23037781330885523f, 0,0,0,0},
  {-0.007800708325034148f, 0.0017677118642428036f, 0.04472490177066578f, -0.021060292512300564f,
   -0.07263752278646252f, 0.3379294217276218f, 0.787641141030194f, 0.4910559419267466f,
   -0.048311742585633f, -0.11799011114819057f, 0.0034907120842174702f, 0.015404109327027373f},
  {-0.08838834764831845f, 0.08838834764831845f, 0.7071067811865476f, 0.7071067811865476f,
    0.08838834764831845f, -0.08838834764831845f, 0,0,0,0,0,0},
};
// dec_hi
constexpr float DHf[4][12] = {
  {-0.7071067811865476f, 0.7071067811865476f, 0,0,0,0,0,0,0,0,0,0},
  {-0.23037781330885523f, 0.7148465705525415f, -0.6308807679295904f, -0.02798376941698385f,
    0.18703481171888114f, 0.030841381835986965f, -0.032883011666982945f, -0.010597401784997278f, 0,0,0,0},
  {-0.015404109327027373f, 0.0034907120842174702f, 0.11799011114819057f, -0.048311742585633f,
   -0.4910559419267466f, 0.787641141030194f, -0.3379294217276218f, -0.07263752278646252f,
    0.021060292512300564f, 0.04472490177066578f, -0.0017677118642428036f, -0.007800708325034148f},
  {0,0,-0.7071067811865476f, 0.7071067811865476f, 0,0, 0,0,0,0,0,0},
};
// rec_lo
constexpr float RLf[4][12] = {
  {0.7071067811865476f, 0.7071067811865476f, 0,0,0,0,0,0,0,0,0,0},
  {0.23037781330885523f, 0.7148465705525415f, 0.6308807679295904f, -0.02798376941698385f,
   -0.18703481171888114f, 0.030841381835986965f, 0.032883011666982945f, -0.010597401784997278f, 0,0,0,0},
  {0.015404109327027373f, 0.0034907120842174702f, -0.11799011114819057f, -0.048311742585633f,
   0.4910559419267466f, 0.787641141030194f, 0.3379294217276218f, -0.07263752278646252f,
   -0.021060292512300564f, 0.04472490177066578f, 0.0017677118642428036f, -0.007800708325034148f},
  {0,0,0.7071067811865476f, 0.7071067811865476f, 0,0, 0,0,0,0,0,0},
};
// rec_hi
constexpr float RHf[4][12] = {
  {0.7071067811865476f, -0.7071067811865476f, 0,0,0,0,0,0,0,0,0,0},
  {-0.010597401784997278f, -0.032883011666982945f, 0.030841381835986965f, 0.18703481171888114f,
   -0.02798376941698385f, -0.6308807679295904f, 0.7148465705525415f, -0.23037781330885523f, 0,0,0,0},
  {-0.007800708325034148f, -0.0017677118642428036f, 0.04472490177066578f, 0.021060292512300564f,
   -0.07263752278646252f, -0.3379294217276218f, 0.787641141030194f, -0.4910559419267466f,
   -0.048311742585633f, 0.11799011114819057f, 0.0034907120842174702f, -0.015404109327027373f},
  {-0.08838834764831845f, -0.08838834764831845f, 0.7071067811865476f, -0.7071067811865476f,
    0.08838834764831845f, 0.08838834764831845f, 0,0,0,0,0,0},
};

__device__ __forceinline__ v2f sv(float c) { return v2f{c, c}; }

// One coefficient index KK of one wavelet W: DWT pair from the shared window,
// shrink, scatter into acc. All indices compile-time (if constexpr recursion).
template <int W, int KK>
__device__ __forceinline__ void step(const v2f (&xw)[36], v2f (&acc)[16],
                                     const v2f la, const v2f ld, const v2f gw) {
  constexpr int L = LW[W];
  if constexpr (KK < L / 2 + 7) {
    v2f lo = {0.f, 0.f}, hi = {0.f, 0.f};
#pragma unroll
    for (int m = 0; m < L; ++m) {
      const v2f xv = xw[2 * KK + 11 - m];
      if (DLf[W][m] != 0.0f) lo += sv(DLf[W][m]) * xv;
      if (DHf[W][m] != 0.0f) hi += sv(DHf[W][m]) * xv;
    }
    v2f cl, ch;
    cl.x = __builtin_amdgcn_fmed3f(lo.x, -la.x, la.x);
    cl.y = __builtin_amdgcn_fmed3f(lo.y, -la.y, la.y);
    ch.x = __builtin_amdgcn_fmed3f(hi.x, -ld.x, ld.x);
    ch.y = __builtin_amdgcn_fmed3f(hi.y, -ld.y, ld.y);
    const v2f loS = (lo - cl) * gw;
    const v2f hiS = (hi - ch) * gw;
#pragma unroll
    for (int m = 0; m < L; ++m) {
      const int j = 2 * KK + m + 2 - L;   // compile-time after unroll
      if (j >= 0 && j < 16) {
        if (RLf[W][m] != 0.0f) acc[j] += loS * sv(RLf[W][m]);
        if (RHf[W][m] != 0.0f) acc[j] += hiS * sv(RHf[W][m]);
      }
    }
  }
}

// Merged sliding pass: at each KK all four wavelets consume the SAME window
// elements xw[2KK..2KK+11], so each window element is globally loaded once and
// stays live ~6 iterations (rolling window ~12 v2f). Residual x injected as
// its element rolls through -> xw liveness ends here, not at the epilogue.
template <int KK>
__device__ __forceinline__ void sweep(const v2f (&xw)[36], v2f (&acc)[16],
                                      const v2f la, const v2f ld,
                                      const v2f gw0, const v2f gw1,
                                      const v2f gw2, const v2f gw3) {
  if constexpr (KK < 13) {
    step<0, KK>(xw, acc, la, ld, gw0);
    step<1, KK>(xw, acc, la, ld, gw1);
    step<2, KK>(xw, acc, la, ld, gw2);
    step<3, KK>(xw, acc, la, ld, gw3);
    if constexpr (KK < 8) {
      acc[2 * KK]     += xw[2 * KK + 10];   // residual y = x + sum w_i rec_i
      acc[2 * KK + 1] += xw[2 * KK + 11];
    }
    sweep<KK + 1>(xw, acc, la, ld, gw0, gw1, gw2, gw3);
  }
}

// No LDS; channel pair (e, e+1) per thread, 16 positions per thread.
__global__ __launch_bounds__(256) void wlm_k1(
    const float* __restrict__ x,
    const float* __restrict__ la_, const float* __restrict__ ld_,
    const float* __restrict__ lg_, const float* __restrict__ th_,
    const float* __restrict__ bl_, float* __restrict__ y) {
  const int tid  = threadIdx.x;
  const int lane = tid & 63;
  const int wave = tid >> 6;
  const int s0 = blockIdx.x * SC;
  const int e0 = blockIdx.y * 128;
  const int b  = blockIdx.z;
  const int e  = e0 + 2 * lane;
  const int sA = s0 + wave * 16;

  // ---- window: x_ref[sA-10 .. sA+25] for channel pair (e, e+1) ----
  const size_t rowb = (size_t)b * T_SEQ;
  v2f xw[36];
  if (sA >= 10 && sA + 26 <= T_SEQ) {
    const float* p = &x[(rowb + sA - 10) * E_DIM + e];
#pragma unroll
    for (int i = 0; i < 36; ++i) {
      xw[i] = *reinterpret_cast<const v2f*>(p + (size_t)i * E_DIM);
    }
  } else {
#pragma unroll
    for (int i = 0; i < 36; ++i) {
      int g = sA - 10 + i;
      g = (g < 0) ? -g : g;
      g = (g >= T_SEQ) ? (2 * T_SEQ - 2 - g) : g;
      xw[i] = *reinterpret_cast<const v2f*>(&x[(rowb + g) * E_DIM + e]);
    }
  }

  // ---- per-channel-pair params ----
  const v2f la = *reinterpret_cast<const v2f*>(&la_[e]);
  const v2f ld = *reinterpret_cast<const v2f*>(&ld_[e]);
  const v2f lg = *reinterpret_cast<const v2f*>(&lg_[e]);
  const v2f th = *reinterpret_cast<const v2f*>(&th_[e]);
  v2f g2;
  g2.x = (fmaxf(lg.x, 0.f) + log1pf(expf(-fabsf(lg.x))) + 1e-6f) * cosf(th.x);
  g2.y = (fmaxf(lg.y, 0.f) + log1pf(expf(-fabsf(lg.y))) + 1e-6f) * cosf(th.y);

  const float b0 = bl_[0], b1 = bl_[1], b2 = bl_[2], b3 = bl_[3];
  const float mx = fmaxf(fmaxf(b0, b1), fmaxf(b2, b3));
  const float w0 = expf(b0 - mx), w1 = expf(b1 - mx),
              w2 = expf(b2 - mx), w3 = expf(b3 - mx);
  const float wr = 1.f / (w0 + w1 + w2 + w3);
  const v2f gw0 = g2 * sv(w0 * wr), gw1 = g2 * sv(w1 * wr),
            gw2 = g2 * sv(w2 * wr), gw3 = g2 * sv(w3 * wr);

  v2f acc[16];
#pragma unroll
  for (int j = 0; j < 16; ++j) acc[j] = v2f{0.f, 0.f};

  sweep<0>(xw, acc, la, ld, gw0, gw1, gw2, gw3);

  // ---- store (residual already folded in during the sweep) ----
#pragma unroll
  for (int j = 0; j < 16; ++j) {
    *reinterpret_cast<v2f*>(&y[(rowb + sA + j) * E_DIM + e]) = acc[j];
  }
}

__global__ __launch_bounds__(256) void wlm_k2(float* __restrict__ y,
                                              const float* __restrict__ w,
                                              const float* __restrict__ bias) {
  const int token = blockIdx.x;
  const int tid = threadIdx.x;
  float* row = y + (size_t)token * E_DIM;

  float4 v = *reinterpret_cast<const float4*>(&row[tid * 4]);
  float s  = v.x + v.y + v.z + v.w;
  float sq = v.x * v.x + v.y * v.y + v.z * v.z + v.w * v.w;
#pragma unroll
  for (int off = 32; off; off >>= 1) {
    s  += __shfl_down(s, off);
    sq += __shfl_down(sq, off);
  }
  __shared__ float ps[4], pq[4], stat[2];
  const int wave = tid >> 6, lane = tid & 63;
  if (lane == 0) { ps[wave] = s; pq[wave] = sq; }
  __syncthreads();
  if (tid == 0) {
    const float S1 = ps[0] + ps[1] + ps[2] + ps[3];
    const float S2 = pq[0] + pq[1] + pq[2] + pq[3];
    const float mu = S1 * (1.f / E_DIM);
    const float var = S2 * (1.f / E_DIM) - mu * mu;
    stat[0] = mu;
    stat[1] = rsqrtf(var + 1e-5f);
  }
  __syncthreads();
  const float mu = stat[0], rstd = stat[1];
  const float4 wv = *reinterpret_cast<const float4*>(&w[tid * 4]);
  const float4 bv = *reinterpret_cast<const float4*>(&bias[tid * 4]);
  float4 o;
  o.x = (v.x - mu) * rstd * wv.x + bv.x;
  o.y = (v.y - mu) * rstd * wv.y + bv.y;
  o.z = (v.z - mu) * rstd * wv.z + bv.z;
  o.w = (v.w - mu) * rstd * wv.w + bv.w;
  *reinterpret_cast<float4*>(&row[tid * 4]) = o;
}

extern "C" void kernel_launch(void* const* d_in, const int* in_sizes, int n_in,
                              void* d_out, int out_size, void* d_ws, size_t ws_size,
                              hipStream_t stream) {
  const float* x   = (const float*)d_in[0];
  const float* la  = (const float*)d_in[1];
  const float* ldt = (const float*)d_in[2];
  const float* lg  = (const float*)d_in[3];
  const float* th  = (const float*)d_in[4];
  const float* bl  = (const float*)d_in[5];
  const float* lnw = (const float*)d_in[6];
  const float* lnb = (const float*)d_in[7];
  float* out = (float*)d_out;

  dim3 g1(T_SEQ / SC, E_DIM / 128, N_B);  // (64, 8, 8)
  wlm_k1<<<g1, 256, 0, stream>>>(x, la, ldt, lg, th, bl, out);
  wlm_k2<<<dim3(N_B * T_SEQ), 256, 0, stream>>>(out, lnw, lnb);
}